// Round 1
// baseline (684.408 us; speedup 1.0000x reference)
//
#include <hip/hip_runtime.h>
#include <hip/hip_bf16.h>
#include <cstdint>
#include <cstddef>

#define Bdim 2
#define Sdim 2048
#define Edim 1024
#define Hdim 16
#define Ddim 64
#define MROWS (Bdim*Sdim)

typedef __bf16 bf16_t;
typedef __attribute__((ext_vector_type(8))) __bf16 bf16x8;
typedef __attribute__((ext_vector_type(4))) float f32x4;

__device__ inline bf16_t f2b(float x) {
    unsigned u = __builtin_bit_cast(unsigned, x);
    unsigned r = u + 0x7fffu + ((u >> 16) & 1u);
    return __builtin_bit_cast(bf16_t, (unsigned short)(r >> 16));
}

// Stage a ROWS x 32 tile (row-major, leading dim ld) into LDS as bf16 with
// rows padded to 40 elements (80 B) to spread banks. Converts f32 -> bf16
// on the fly when T == float.
template<typename T, int ROWS>
__device__ inline void stage_tile(bf16_t* dst, const T* src, int ld, int tid) {
    for (int i = tid; i < ROWS * 4; i += 256) {
        int r = i >> 2;
        int c = (i & 3) * 8;
        const T* s = src + (size_t)r * ld + c;
        bf16x8 v;
        if constexpr (sizeof(T) == 4) {
            const float4* sf = (const float4*)s;
            float4 a = sf[0], b = sf[1];
            v[0] = f2b(a.x); v[1] = f2b(a.y); v[2] = f2b(a.z); v[3] = f2b(a.w);
            v[4] = f2b(b.x); v[5] = f2b(b.y); v[6] = f2b(b.z); v[7] = f2b(b.w);
        } else {
            v = *(const bf16x8*)s;
        }
        *(bf16x8*)(dst + r * 40 + c) = v;
    }
}

// Core: C[128 x BN] += A[128 x K] * B^T where B is stored row-major [BN x K]
// (i.e. B rows are the K-dim, contiguous). BN = FN*32, 4 waves in 2x2 grid,
// each wave owns 64 x (FN*16), 4 x FN fragments of 16x16, mfma 16x16x32 bf16.
template<typename TA, typename TB, int FN>
__device__ inline void gemm_core(const TA* A, int lda, const TB* B, int ldb, int K,
                                 f32x4 (&acc)[4][FN]) {
    constexpr int BN = FN * 32;
    __shared__ bf16_t As[128 * 40];
    __shared__ bf16_t Bs[BN * 40];
    const int tid = threadIdx.x;
    const int lane = tid & 63;
    const int w = tid >> 6;
    const int wm = w >> 1, wn = w & 1;
    const int lr = lane & 15, lg = lane >> 4;

    #pragma unroll
    for (int mi = 0; mi < 4; ++mi)
        #pragma unroll
        for (int ni = 0; ni < FN; ++ni)
            acc[mi][ni] = (f32x4){0.f, 0.f, 0.f, 0.f};

    for (int kt = 0; kt < K; kt += 32) {
        __syncthreads();
        stage_tile<TA, 128>(As, A + kt, lda, tid);
        stage_tile<TB, BN>(Bs, B + kt, ldb, tid);
        __syncthreads();
        bf16x8 af[4], bf[FN];
        #pragma unroll
        for (int mi = 0; mi < 4; ++mi)
            af[mi] = *(const bf16x8*)&As[(wm * 64 + mi * 16 + lr) * 40 + lg * 8];
        #pragma unroll
        for (int ni = 0; ni < FN; ++ni)
            bf[ni] = *(const bf16x8*)&Bs[(wn * (FN * 16) + ni * 16 + lr) * 40 + lg * 8];
        #pragma unroll
        for (int mi = 0; mi < 4; ++mi)
            #pragma unroll
            for (int ni = 0; ni < FN; ++ni)
                acc[mi][ni] = __builtin_amdgcn_mfma_f32_16x16x32_bf16(
                    af[mi], bf[ni], acc[mi][ni], 0, 0, 0);
    }
}

// ---- Kernel 1: QKV projections. z = 0/1/2 -> Q/K/V.
// Q,K -> [B,H,S,D] bf16; V -> transposed [B,H,D,S] bf16 (for PV B^T access).
__global__ __launch_bounds__(256) void k_proj(
    const float* __restrict__ xq, const float* __restrict__ xk, const float* __restrict__ xv,
    const float* __restrict__ wq, const float* __restrict__ wk, const float* __restrict__ wv,
    const float* __restrict__ bq, const float* __restrict__ bk, const float* __restrict__ bv,
    bf16_t* __restrict__ Qb, bf16_t* __restrict__ Kb, bf16_t* __restrict__ Vtb) {
    const int z = blockIdx.z;
    const float* X = (z == 0) ? xq : (z == 1) ? xk : xv;
    const float* W = (z == 0) ? wq : (z == 1) ? wk : wv;
    const float* bias = (z == 0) ? bq : (z == 1) ? bk : bv;
    const int tm = blockIdx.y, tn = blockIdx.x;
    f32x4 acc[4][4];
    gemm_core<float, float, 4>(X + (size_t)tm * 128 * Edim, Edim,
                               W + (size_t)tn * 128 * Edim, Edim, Edim, acc);
    const int tid = threadIdx.x, lane = tid & 63, w = tid >> 6;
    const int wm = w >> 1, wn = w & 1, lr = lane & 15, lg = lane >> 4;
    #pragma unroll
    for (int mi = 0; mi < 4; ++mi)
        #pragma unroll
        for (int ni = 0; ni < 4; ++ni)
            #pragma unroll
            for (int j = 0; j < 4; ++j) {
                int gm = tm * 128 + wm * 64 + mi * 16 + lg * 4 + j;
                int gn = tn * 128 + wn * 64 + ni * 16 + lr;
                float v = acc[mi][ni][j] + bias[gn];
                int b = gm >> 11, s = gm & (Sdim - 1);
                int h = gn >> 6, d = gn & (Ddim - 1);
                if (z == 2)
                    Vtb[((size_t)(b * Hdim + h) * Ddim + d) * Sdim + s] = f2b(v);
                else if (z == 0)
                    Qb[((size_t)(b * Hdim + h) * Sdim + s) * Ddim + d] = f2b(v);
                else
                    Kb[((size_t)(b * Hdim + h) * Sdim + s) * Ddim + d] = f2b(v);
            }
}

// ---- Kernel 2: raw scores = Q K^T * 1/sqrt(D) -> f32 into d_out attn region.
__global__ __launch_bounds__(256) void k_scores(
    const bf16_t* __restrict__ Qb, const bf16_t* __restrict__ Kb, float* __restrict__ P) {
    const int bh = blockIdx.z;
    f32x4 acc[4][4];
    gemm_core<bf16_t, bf16_t, 4>(
        Qb + (size_t)bh * Sdim * Ddim + (size_t)blockIdx.y * 128 * Ddim, Ddim,
        Kb + (size_t)bh * Sdim * Ddim + (size_t)blockIdx.x * 128 * Ddim, Ddim, Ddim, acc);
    float* Pp = P + (size_t)bh * Sdim * Sdim;
    const int tid = threadIdx.x, lane = tid & 63, w = tid >> 6;
    const int wm = w >> 1, wn = w & 1, lr = lane & 15, lg = lane >> 4;
    #pragma unroll
    for (int mi = 0; mi < 4; ++mi)
        #pragma unroll
        for (int ni = 0; ni < 4; ++ni)
            #pragma unroll
            for (int j = 0; j < 4; ++j) {
                int gm = blockIdx.y * 128 + wm * 64 + mi * 16 + lg * 4 + j;
                int gn = blockIdx.x * 128 + wn * 64 + ni * 16 + lr;
                Pp[(size_t)gm * Sdim + gn] = acc[mi][ni][j] * 0.125f;
            }
}

// ---- Kernel 3: in-place row softmax over P rows of length 2048.
__global__ __launch_bounds__(256) void k_softmax(float* __restrict__ P) {
    float* p = P + (size_t)blockIdx.x * Sdim;
    const int t = threadIdx.x;
    float4* pv = (float4*)p;
    float4 v0 = pv[2 * t], v1 = pv[2 * t + 1];
    float m = fmaxf(fmaxf(fmaxf(v0.x, v0.y), fmaxf(v0.z, v0.w)),
                    fmaxf(fmaxf(v1.x, v1.y), fmaxf(v1.z, v1.w)));
    #pragma unroll
    for (int off = 32; off > 0; off >>= 1) m = fmaxf(m, __shfl_xor(m, off));
    __shared__ float redm[4], reds[4];
    if ((t & 63) == 0) redm[t >> 6] = m;
    __syncthreads();
    m = fmaxf(fmaxf(redm[0], redm[1]), fmaxf(redm[2], redm[3]));
    v0.x = __expf(v0.x - m); v0.y = __expf(v0.y - m);
    v0.z = __expf(v0.z - m); v0.w = __expf(v0.w - m);
    v1.x = __expf(v1.x - m); v1.y = __expf(v1.y - m);
    v1.z = __expf(v1.z - m); v1.w = __expf(v1.w - m);
    float s = v0.x + v0.y + v0.z + v0.w + v1.x + v1.y + v1.z + v1.w;
    #pragma unroll
    for (int off = 32; off > 0; off >>= 1) s += __shfl_xor(s, off);
    if ((t & 63) == 0) reds[t >> 6] = s;
    __syncthreads();
    s = reds[0] + reds[1] + reds[2] + reds[3];
    float inv = 1.0f / s;
    v0.x *= inv; v0.y *= inv; v0.z *= inv; v0.w *= inv;
    v1.x *= inv; v1.y *= inv; v1.z *= inv; v1.w *= inv;
    pv[2 * t] = v0; pv[2 * t + 1] = v1;
}

// ---- Kernel 4: attn_out = P @ V  (P f32 cast to bf16 in staging; V stored
// transposed [B,H,D,S]). Output -> AOb [B,S,E] bf16. BN = 64 (FN = 2).
__global__ __launch_bounds__(256) void k_pv(
    const float* __restrict__ P, const bf16_t* __restrict__ Vtb, bf16_t* __restrict__ AOb) {
    const int bh = blockIdx.z, b = bh >> 4, h = bh & 15;
    f32x4 acc[4][2];
    gemm_core<float, bf16_t, 2>(
        P + (size_t)bh * Sdim * Sdim + (size_t)blockIdx.y * 128 * Sdim, Sdim,
        Vtb + (size_t)bh * Ddim * Sdim, Sdim, Sdim, acc);
    const int tid = threadIdx.x, lane = tid & 63, w = tid >> 6;
    const int wm = w >> 1, wn = w & 1, lr = lane & 15, lg = lane >> 4;
    #pragma unroll
    for (int mi = 0; mi < 4; ++mi)
        #pragma unroll
        for (int ni = 0; ni < 2; ++ni)
            #pragma unroll
            for (int j = 0; j < 4; ++j) {
                int gm = blockIdx.y * 128 + wm * 64 + mi * 16 + lg * 4 + j;   // s
                int gn = wn * 32 + ni * 16 + lr;                              // d
                AOb[((size_t)(b * Sdim + gm)) * Edim + h * Ddim + gn] = f2b(acc[mi][ni][j]);
            }
}

// ---- Kernel 5: output = AO @ Wo^T + bo -> d_out f32.
__global__ __launch_bounds__(256) void k_oproj(
    const bf16_t* __restrict__ AOb, const float* __restrict__ Wo, const float* __restrict__ bo,
    float* __restrict__ out) {
    f32x4 acc[4][4];
    gemm_core<bf16_t, float, 4>(AOb + (size_t)blockIdx.y * 128 * Edim, Edim,
                                Wo + (size_t)blockIdx.x * 128 * Edim, Edim, Edim, acc);
    const int tid = threadIdx.x, lane = tid & 63, w = tid >> 6;
    const int wm = w >> 1, wn = w & 1, lr = lane & 15, lg = lane >> 4;
    #pragma unroll
    for (int mi = 0; mi < 4; ++mi)
        #pragma unroll
        for (int ni = 0; ni < 4; ++ni)
            #pragma unroll
            for (int j = 0; j < 4; ++j) {
                int gm = blockIdx.y * 128 + wm * 64 + mi * 16 + lg * 4 + j;
                int gn = blockIdx.x * 128 + wn * 64 + ni * 16 + lr;
                out[(size_t)gm * Edim + gn] = acc[mi][ni][j] + bo[gn];
            }
}

extern "C" void kernel_launch(void* const* d_in, const int* in_sizes, int n_in,
                              void* d_out, int out_size, void* d_ws, size_t ws_size,
                              hipStream_t stream) {
    const float* query = (const float*)d_in[0];
    const float* key_  = (const float*)d_in[1];
    const float* value = (const float*)d_in[2];
    const float* Wq = (const float*)d_in[3];
    const float* bq = (const float*)d_in[4];
    const float* Wk = (const float*)d_in[5];
    const float* bk = (const float*)d_in[6];
    const float* Wv = (const float*)d_in[7];
    const float* bv = (const float*)d_in[8];
    const float* Wo = (const float*)d_in[9];
    const float* bo = (const float*)d_in[10];

    float* out = (float*)d_out;                      // [4096][1024]
    float* P = out + (size_t)MROWS * Edim;           // [32][2048][2048] attn weights

    const size_t HSD = (size_t)Bdim * Hdim * Sdim * Ddim;  // 4M elems
    bf16_t* Qb  = (bf16_t*)d_ws;        // [B,H,S,D]
    bf16_t* Kb  = Qb + HSD;             // [B,H,S,D]
    bf16_t* Vtb = Kb + HSD;             // [B,H,D,S]
    bf16_t* AOb = Vtb + HSD;            // [B,S,E]

    k_proj<<<dim3(8, 32, 3), 256, 0, stream>>>(query, key_, value, Wq, Wk, Wv,
                                               bq, bk, bv, Qb, Kb, Vtb);
    k_scores<<<dim3(16, 16, 32), 256, 0, stream>>>(Qb, Kb, P);
    k_softmax<<<dim3(Bdim * Hdim * Sdim), 256, 0, stream>>>(P);
    k_pv<<<dim3(1, 16, 32), 256, 0, stream>>>(P, Vtb, AOb);
    k_oproj<<<dim3(8, 32, 1), 256, 0, stream>>>(AOb, Wo, bo, out);
}

// Round 2
// 414.122 us; speedup vs baseline: 1.6527x; 1.6527x over previous
//
#include <hip/hip_runtime.h>
#include <hip/hip_bf16.h>
#include <cstdint>
#include <cstddef>

#define Bdim 2
#define Sdim 2048
#define Edim 1024
#define Hdim 16
#define Ddim 64
#define MROWS (Bdim*Sdim)

typedef __bf16 bf16_t;
typedef __attribute__((ext_vector_type(8))) __bf16 bf16x8;
typedef __attribute__((ext_vector_type(4))) float f32x4;

__device__ inline bf16_t f2b(float x) {
    unsigned u = __builtin_bit_cast(unsigned, x);
    unsigned r = u + 0x7fffu + ((u >> 16) & 1u);
    return __builtin_bit_cast(bf16_t, (unsigned short)(r >> 16));
}

// Stage a ROWS x 32 tile (row-major, leading dim ld) into LDS as bf16, rows
// padded to 40 elements. Converts f32 -> bf16 on the fly when T == float.
template<typename T, int ROWS>
__device__ inline void stage_tile(bf16_t* dst, const T* src, int ld, int tid) {
    for (int i = tid; i < ROWS * 4; i += 256) {
        int r = i >> 2;
        int c = (i & 3) * 8;
        const T* s = src + (size_t)r * ld + c;
        bf16x8 v;
        if constexpr (sizeof(T) == 4) {
            const float4* sf = (const float4*)s;
            float4 a = sf[0], b = sf[1];
            v[0] = f2b(a.x); v[1] = f2b(a.y); v[2] = f2b(a.z); v[3] = f2b(a.w);
            v[4] = f2b(b.x); v[5] = f2b(b.y); v[6] = f2b(b.z); v[7] = f2b(b.w);
        } else {
            v = *(const bf16x8*)s;
        }
        *(bf16x8*)(dst + r * 40 + c) = v;
    }
}

// Core: C[128 x BN] += A[128 x K] * B^T, B row-major [BN x K]. 4 waves 2x2.
template<typename TA, typename TB, int FN>
__device__ inline void gemm_core(const TA* A, int lda, const TB* B, int ldb, int K,
                                 f32x4 (&acc)[4][FN]) {
    constexpr int BN = FN * 32;
    __shared__ bf16_t As[128 * 40];
    __shared__ bf16_t Bs[BN * 40];
    const int tid = threadIdx.x;
    const int lane = tid & 63;
    const int w = tid >> 6;
    const int wm = w >> 1, wn = w & 1;
    const int lr = lane & 15, lg = lane >> 4;

    #pragma unroll
    for (int mi = 0; mi < 4; ++mi)
        #pragma unroll
        for (int ni = 0; ni < FN; ++ni)
            acc[mi][ni] = (f32x4){0.f, 0.f, 0.f, 0.f};

    for (int kt = 0; kt < K; kt += 32) {
        __syncthreads();
        stage_tile<TA, 128>(As, A + kt, lda, tid);
        stage_tile<TB, BN>(Bs, B + kt, ldb, tid);
        __syncthreads();
        bf16x8 af[4], bf[FN];
        #pragma unroll
        for (int mi = 0; mi < 4; ++mi)
            af[mi] = *(const bf16x8*)&As[(wm * 64 + mi * 16 + lr) * 40 + lg * 8];
        #pragma unroll
        for (int ni = 0; ni < FN; ++ni)
            bf[ni] = *(const bf16x8*)&Bs[(wn * (FN * 16) + ni * 16 + lr) * 40 + lg * 8];
        #pragma unroll
        for (int mi = 0; mi < 4; ++mi)
            #pragma unroll
            for (int ni = 0; ni < FN; ++ni)
                acc[mi][ni] = __builtin_amdgcn_mfma_f32_16x16x32_bf16(
                    af[mi], bf[ni], acc[mi][ni], 0, 0, 0);
    }
}

// ---- Kernel 1: QKV projections. z = 0/1/2 -> Q/K/V.
// Q,K -> [B,H,S,D] bf16; V -> transposed [B,H,D,S] bf16.
__global__ __launch_bounds__(256) void k_proj(
    const float* __restrict__ xq, const float* __restrict__ xk, const float* __restrict__ xv,
    const float* __restrict__ wq, const float* __restrict__ wk, const float* __restrict__ wv,
    const float* __restrict__ bq, const float* __restrict__ bk, const float* __restrict__ bv,
    bf16_t* __restrict__ Qb, bf16_t* __restrict__ Kb, bf16_t* __restrict__ Vtb) {
    const int z = blockIdx.z;
    const float* X = (z == 0) ? xq : (z == 1) ? xk : xv;
    const float* W = (z == 0) ? wq : (z == 1) ? wk : wv;
    const float* bias = (z == 0) ? bq : (z == 1) ? bk : bv;
    const int tm = blockIdx.y, tn = blockIdx.x;
    f32x4 acc[4][4];
    gemm_core<float, float, 4>(X + (size_t)tm * 128 * Edim, Edim,
                               W + (size_t)tn * 128 * Edim, Edim, Edim, acc);
    const int tid = threadIdx.x, lane = tid & 63, w = tid >> 6;
    const int wm = w >> 1, wn = w & 1, lr = lane & 15, lg = lane >> 4;
    #pragma unroll
    for (int mi = 0; mi < 4; ++mi)
        #pragma unroll
        for (int ni = 0; ni < 4; ++ni)
            #pragma unroll
            for (int j = 0; j < 4; ++j) {
                int gm = tm * 128 + wm * 64 + mi * 16 + lg * 4 + j;
                int gn = tn * 128 + wn * 64 + ni * 16 + lr;
                float v = acc[mi][ni][j] + bias[gn];
                int b = gm >> 11, s = gm & (Sdim - 1);
                int h = gn >> 6, d = gn & (Ddim - 1);
                if (z == 2)
                    Vtb[((size_t)(b * Hdim + h) * Ddim + d) * Sdim + s] = f2b(v);
                else if (z == 0)
                    Qb[((size_t)(b * Hdim + h) * Sdim + s) * Ddim + d] = f2b(v);
                else
                    Kb[((size_t)(b * Hdim + h) * Sdim + s) * Ddim + d] = f2b(v);
            }
}

// ---- Kernel 2: fused attention. Per (q-tile of 128 rows, bh):
// phase 1: online max/sum of scores (S recomputed, discarded);
// phase 2: recompute S, write normalized P (f32, to d_out), accumulate O=P.V.
__global__ __launch_bounds__(256) void k_attn(
    const bf16_t* __restrict__ Qb, const bf16_t* __restrict__ Kb,
    const bf16_t* __restrict__ Vtb, float* __restrict__ P, bf16_t* __restrict__ AOb) {
    const int bh = blockIdx.y, b = bh >> 4, h = bh & 15;
    const int qt = blockIdx.x;
    const int tid = threadIdx.x, lane = tid & 63, w = tid >> 6;
    const int wm = w >> 1, wn = w & 1, lr = lane & 15, lg = lane >> 4;

    __shared__ bf16_t Ps[128 * 136];
    __shared__ float pm[2][128], ps[2][128], bm[128], bl[128];

    const bf16_t* Qp = Qb + ((size_t)bh * Sdim + (size_t)qt * 128) * Ddim;
    const bf16_t* Kp = Kb + (size_t)bh * Sdim * Ddim;
    const bf16_t* Vp = Vtb + (size_t)bh * Ddim * Sdim;
    float* Pp = P + (size_t)bh * Sdim * Sdim;

    // Q fragments for this wave's 64 q-rows, pre-scaled by 1/sqrt(D)=0.125.
    bf16x8 qf[4][2];
    #pragma unroll
    for (int mi = 0; mi < 4; ++mi)
        #pragma unroll
        for (int kk = 0; kk < 2; ++kk) {
            bf16x8 v = *(const bf16x8*)(Qp + (wm * 64 + mi * 16 + lr) * Ddim + kk * 32 + lg * 8);
            #pragma unroll
            for (int e = 0; e < 8; ++e) v[e] = f2b(0.125f * (float)v[e]);
            qf[mi][kk] = v;
        }

    float m_r = -1e30f, l_r = 0.f;

    // ---------------- Phase 1: stats ----------------
    for (int kt = 0; kt < Sdim / 128; ++kt) {
        bf16x8 kf[4][2];
        #pragma unroll
        for (int ni = 0; ni < 4; ++ni)
            #pragma unroll
            for (int kk = 0; kk < 2; ++kk)
                kf[ni][kk] = *(const bf16x8*)(Kp + (size_t)(kt * 128 + wn * 64 + ni * 16 + lr) * Ddim + kk * 32 + lg * 8);
        f32x4 sacc[4][4];
        #pragma unroll
        for (int mi = 0; mi < 4; ++mi)
            #pragma unroll
            for (int ni = 0; ni < 4; ++ni)
                sacc[mi][ni] = (f32x4){0.f, 0.f, 0.f, 0.f};
        #pragma unroll
        for (int kk = 0; kk < 2; ++kk)
            #pragma unroll
            for (int mi = 0; mi < 4; ++mi)
                #pragma unroll
                for (int ni = 0; ni < 4; ++ni)
                    sacc[mi][ni] = __builtin_amdgcn_mfma_f32_16x16x32_bf16(
                        qf[mi][kk], kf[ni][kk], sacc[mi][ni], 0, 0, 0);
        // per-row tile max
        float rmax[4][4];
        #pragma unroll
        for (int mi = 0; mi < 4; ++mi)
            #pragma unroll
            for (int j = 0; j < 4; ++j) {
                float v = fmaxf(fmaxf(sacc[mi][0][j], sacc[mi][1][j]),
                                fmaxf(sacc[mi][2][j], sacc[mi][3][j]));
                rmax[mi][j] = v;
            }
        #pragma unroll
        for (int mask = 1; mask <= 8; mask <<= 1)
            #pragma unroll
            for (int mi = 0; mi < 4; ++mi)
                #pragma unroll
                for (int j = 0; j < 4; ++j)
                    rmax[mi][j] = fmaxf(rmax[mi][j], __shfl_xor(rmax[mi][j], mask));
        if (lr == 0)
            #pragma unroll
            for (int mi = 0; mi < 4; ++mi)
                #pragma unroll
                for (int j = 0; j < 4; ++j)
                    pm[wn][wm * 64 + mi * 16 + lg * 4 + j] = rmax[mi][j];
        __syncthreads();
        if (tid < 128) {
            float t = fmaxf(pm[0][tid], pm[1][tid]);
            float mnew = fmaxf(m_r, t);
            l_r *= __expf(m_r - mnew);
            m_r = mnew;
            bm[tid] = mnew;
        }
        __syncthreads();
        float rsum[4][4];
        #pragma unroll
        for (int mi = 0; mi < 4; ++mi)
            #pragma unroll
            for (int j = 0; j < 4; ++j) {
                float mrow = bm[wm * 64 + mi * 16 + lg * 4 + j];
                float s = 0.f;
                #pragma unroll
                for (int ni = 0; ni < 4; ++ni) s += __expf(sacc[mi][ni][j] - mrow);
                rsum[mi][j] = s;
            }
        #pragma unroll
        for (int mask = 1; mask <= 8; mask <<= 1)
            #pragma unroll
            for (int mi = 0; mi < 4; ++mi)
                #pragma unroll
                for (int j = 0; j < 4; ++j)
                    rsum[mi][j] += __shfl_xor(rsum[mi][j], mask);
        if (lr == 0)
            #pragma unroll
            for (int mi = 0; mi < 4; ++mi)
                #pragma unroll
                for (int j = 0; j < 4; ++j)
                    ps[wn][wm * 64 + mi * 16 + lg * 4 + j] = rsum[mi][j];
        __syncthreads();
        if (tid < 128) l_r += ps[0][tid] + ps[1][tid];
        __syncthreads();
    }

    if (tid < 128) { bm[tid] = m_r; bl[tid] = 1.0f / l_r; }
    __syncthreads();

    // ---------------- Phase 2: P write + O = P.V ----------------
    f32x4 oacc[4][2];
    #pragma unroll
    for (int mi = 0; mi < 4; ++mi)
        #pragma unroll
        for (int ni = 0; ni < 2; ++ni)
            oacc[mi][ni] = (f32x4){0.f, 0.f, 0.f, 0.f};

    for (int kt = 0; kt < Sdim / 128; ++kt) {
        bf16x8 kf[4][2];
        #pragma unroll
        for (int ni = 0; ni < 4; ++ni)
            #pragma unroll
            for (int kk = 0; kk < 2; ++kk)
                kf[ni][kk] = *(const bf16x8*)(Kp + (size_t)(kt * 128 + wn * 64 + ni * 16 + lr) * Ddim + kk * 32 + lg * 8);
        f32x4 sacc[4][4];
        #pragma unroll
        for (int mi = 0; mi < 4; ++mi)
            #pragma unroll
            for (int ni = 0; ni < 4; ++ni)
                sacc[mi][ni] = (f32x4){0.f, 0.f, 0.f, 0.f};
        #pragma unroll
        for (int kk = 0; kk < 2; ++kk)
            #pragma unroll
            for (int mi = 0; mi < 4; ++mi)
                #pragma unroll
                for (int ni = 0; ni < 4; ++ni)
                    sacc[mi][ni] = __builtin_amdgcn_mfma_f32_16x16x32_bf16(
                        qf[mi][kk], kf[ni][kk], sacc[mi][ni], 0, 0, 0);
        // normalized P: write f32 to global + bf16 to LDS
        #pragma unroll
        for (int mi = 0; mi < 4; ++mi)
            #pragma unroll
            for (int j = 0; j < 4; ++j) {
                int row = wm * 64 + mi * 16 + lg * 4 + j;
                float mrow = bm[row], il = bl[row];
                size_t gr = (size_t)(qt * 128 + row) * Sdim + kt * 128;
                #pragma unroll
                for (int ni = 0; ni < 4; ++ni) {
                    int col = wn * 64 + ni * 16 + lr;
                    float p = __expf(sacc[mi][ni][j] - mrow) * il;
                    Pp[gr + col] = p;
                    Ps[row * 136 + col] = f2b(p);
                }
            }
        __syncthreads();
        // O += P.V for this k-tile
        #pragma unroll
        for (int ks = 0; ks < 4; ++ks) {
            bf16x8 pa[4], vf[2];
            #pragma unroll
            for (int mi = 0; mi < 4; ++mi)
                pa[mi] = *(const bf16x8*)&Ps[(wm * 64 + mi * 16 + lr) * 136 + ks * 32 + lg * 8];
            #pragma unroll
            for (int ni = 0; ni < 2; ++ni)
                vf[ni] = *(const bf16x8*)(Vp + (size_t)(wn * 32 + ni * 16 + lr) * Sdim + kt * 128 + ks * 32 + lg * 8);
            #pragma unroll
            for (int mi = 0; mi < 4; ++mi)
                #pragma unroll
                for (int ni = 0; ni < 2; ++ni)
                    oacc[mi][ni] = __builtin_amdgcn_mfma_f32_16x16x32_bf16(
                        pa[mi], vf[ni], oacc[mi][ni], 0, 0, 0);
        }
        __syncthreads();
    }

    // epilogue: AO bf16 [B,S,E]
    #pragma unroll
    for (int mi = 0; mi < 4; ++mi)
        #pragma unroll
        for (int ni = 0; ni < 2; ++ni)
            #pragma unroll
            for (int j = 0; j < 4; ++j) {
                int s = qt * 128 + wm * 64 + mi * 16 + lg * 4 + j;
                int d = wn * 32 + ni * 16 + lr;
                AOb[((size_t)(b * Sdim + s)) * Edim + h * Ddim + d] = f2b(oacc[mi][ni][j]);
            }
}

// ---- Kernel 3: output = AO @ Wo^T + bo -> d_out f32.
__global__ __launch_bounds__(256) void k_oproj(
    const bf16_t* __restrict__ AOb, const float* __restrict__ Wo, const float* __restrict__ bo,
    float* __restrict__ out) {
    f32x4 acc[4][4];
    gemm_core<bf16_t, float, 4>(AOb + (size_t)blockIdx.y * 128 * Edim, Edim,
                                Wo + (size_t)blockIdx.x * 128 * Edim, Edim, Edim, acc);
    const int tid = threadIdx.x, lane = tid & 63, w = tid >> 6;
    const int wm = w >> 1, wn = w & 1, lr = lane & 15, lg = lane >> 4;
    #pragma unroll
    for (int mi = 0; mi < 4; ++mi)
        #pragma unroll
        for (int ni = 0; ni < 4; ++ni)
            #pragma unroll
            for (int j = 0; j < 4; ++j) {
                int gm = blockIdx.y * 128 + wm * 64 + mi * 16 + lg * 4 + j;
                int gn = blockIdx.x * 128 + wn * 64 + ni * 16 + lr;
                out[(size_t)gm * Edim + gn] = acc[mi][ni][j] + bo[gn];
            }
}

extern "C" void kernel_launch(void* const* d_in, const int* in_sizes, int n_in,
                              void* d_out, int out_size, void* d_ws, size_t ws_size,
                              hipStream_t stream) {
    const float* query = (const float*)d_in[0];
    const float* key_  = (const float*)d_in[1];
    const float* value = (const float*)d_in[2];
    const float* Wq = (const float*)d_in[3];
    const float* bq = (const float*)d_in[4];
    const float* Wk = (const float*)d_in[5];
    const float* bk = (const float*)d_in[6];
    const float* Wv = (const float*)d_in[7];
    const float* bv = (const float*)d_in[8];
    const float* Wo = (const float*)d_in[9];
    const float* bo = (const float*)d_in[10];

    float* out = (float*)d_out;                      // [4096][1024]
    float* P = out + (size_t)MROWS * Edim;           // [32][2048][2048] attn weights

    const size_t HSD = (size_t)Bdim * Hdim * Sdim * Ddim;  // 4M elems
    bf16_t* Qb  = (bf16_t*)d_ws;        // [B,H,S,D]
    bf16_t* Kb  = Qb + HSD;             // [B,H,S,D]
    bf16_t* Vtb = Kb + HSD;             // [B,H,D,S]
    bf16_t* AOb = Vtb + HSD;            // [B,S,E]

    k_proj<<<dim3(8, 32, 3), 256, 0, stream>>>(query, key_, value, Wq, Wk, Wv,
                                               bq, bk, bv, Qb, Kb, Vtb);
    k_attn<<<dim3(16, 32), 256, 0, stream>>>(Qb, Kb, Vtb, P, AOb);
    k_oproj<<<dim3(8, 32, 1), 256, 0, stream>>>(AOb, Wo, bo, out);
}